// Round 1
// baseline (67.891 us; speedup 1.0000x reference)
//
#include <hip/hip_runtime.h>
#include <hip/hip_bf16.h>
#include <math.h>

// Problem constants (B,U,D) = (4096, 256, 128)
#define BN 4096
#define UN 256
#define DN 128
#define MROW 16        // batch rows per block (one M=16 MFMA tile)
#define BLOCK 1024     // 16 waves: wave w owns u-tile w
#define LSTRIDE 260    // logits row stride; 260 % 32 == 4 -> 2-way banks (free)

typedef __attribute__((ext_vector_type(8))) short short8x;   // 8 bf16
typedef __attribute__((ext_vector_type(4))) float float4x;   // MFMA C/D

__device__ inline uint pack2bf(float a, float b) {
    __hip_bfloat16 ha = __float2bfloat16(a);
    __hip_bfloat16 hb = __float2bfloat16(b);
    return (uint)(*(ushort*)&ha) | ((uint)(*(ushort*)&hb) << 16);
}

// Single fused kernel: no prep launch, no workspace.
// Each wave w owns u-tile w (u = w*16 + m16). It loads its own W/bias rows
// as f32 directly from global (L2/L3-resident, 32B/lane/ks), converts to
// bf16 B-fragments in-register, and computes per-u epilogue scalars with
// per-lane FMA chains + shfl_xor(16/32) over the q-groups.
// Fragment check: lane (q,m16) holds W[u][ks*32 + q*8 .. +8] — identical to
// the layout prep_wb used to materialize in the workspace.
__global__ __launch_bounds__(BLOCK, 4) void fused_kernel(
    const float* __restrict__ x, const float* __restrict__ W,
    const float* __restrict__ bias, float* __restrict__ out)
{
    __shared__ __align__(16) uint XL[MROW * DN / 2];   // 4 KB, bf16 fragment order
    __shared__ float nv2_lds[MROW];
    __shared__ float logits[MROW][LSTRIDE];            // ~16.6 KB

    const int t    = threadIdx.x;
    const int lane = t & 63;
    const int wave = t >> 6;          // u-tile index; also x-row during staging
    const int m16  = lane & 15;
    const int q    = lane >> 4;
    const int b0   = blockIdx.x * MROW;
    const int u    = wave * 16 + m16;

    // ---- issue the x-row load first (it is the critical path to the barrier)
    const int d0x = lane * 2;
    const float2 xv = *(const float2*)(x + (size_t)(b0 + wave) * DN + d0x);

    // ---- issue all W/bias f32 fragment loads (16x dwordx4 per lane)
    const float4* Wrow = (const float4*)(W    + (size_t)u * DN);
    const float4* Brow = (const float4*)(bias + (size_t)u * DN);
    float4 wv[8], bv[8];
    #pragma unroll
    for (int ks = 0; ks < 4; ++ks) {
        const int c = ks * 8 + q * 2;      // float4 index: (ks*32 + q*8)/4
        wv[2*ks  ] = Wrow[c    ];
        wv[2*ks+1] = Wrow[c + 1];
        bv[2*ks  ] = Brow[c    ];
        bv[2*ks+1] = Brow[c + 1];
    }

    // ---- stage x tile into LDS (bf16 fragment order) + exact f32 ||x||^2
    {
        float sq = fmaf(xv.x, xv.x, xv.y * xv.y);
        #pragma unroll
        for (int off = 32; off; off >>= 1) sq += __shfl_xor(sq, off);
        if (lane == 0) nv2_lds[wave] = sq;
        const int ks = d0x >> 5, qq = (d0x & 31) >> 3;
        XL[(ks * 64 + qq * 16 + wave) * 4 + ((d0x & 7) >> 1)] = pack2bf(xv.x, xv.y);
    }

    // ---- in-register prep: bf16 B-fragments + per-u scalar partials
    float nb2 = 0.f, bw = 0.f, wn2 = 0.f;
    short8x wf[4], bf[4];
    #pragma unroll
    for (int ks = 0; ks < 4; ++ks) {
        const float* wp = (const float*)&wv[2*ks];
        const float* bp = (const float*)&bv[2*ks];
        uint wpk[4], bpk[4];
        #pragma unroll
        for (int p = 0; p < 4; ++p) {
            const float w0 = wp[2*p], w1 = wp[2*p+1];
            const float c0 = bp[2*p], c1 = bp[2*p+1];
            wn2 = fmaf(w0, w0, fmaf(w1, w1, wn2));
            nb2 = fmaf(c0, c0, fmaf(c1, c1, nb2));
            bw  = fmaf(c0, w0, fmaf(c1, w1, bw));
            wpk[p] = pack2bf(w0, w1);
            bpk[p] = pack2bf(c0, c1);
        }
        wf[ks] = *(const short8x*)wpk;
        bf[ks] = *(const short8x*)bpk;
    }
    // reduce over the 4 q-groups: lanes {m16, m16+16, m16+32, m16+48} share u
    nb2 += __shfl_xor(nb2, 16);  bw += __shfl_xor(bw, 16);  wn2 += __shfl_xor(wn2, 16);
    nb2 += __shfl_xor(nb2, 32);  bw += __shfl_xor(bw, 32);  wn2 += __shfl_xor(wn2, 32);
    const float one_m  = 1.0f - nb2;
    const float a_norm = fabsf(one_m) * sqrtf(wn2);
    const float scale  = (2.0f / one_m) * a_norm;

    __syncthreads();

    // ---- A-fragments from LDS + MFMA
    const float4 nv4 = ((const float4*)nv2_lds)[q]; // rows q*4..q*4+3
    float4x accW = {0.f, 0.f, 0.f, 0.f};
    float4x accB = {0.f, 0.f, 0.f, 0.f};
    #pragma unroll
    for (int ks = 0; ks < 4; ++ks) {
        const short8x af = *(const short8x*)&XL[(ks * 64 + lane) * 4];
        accW = __builtin_amdgcn_mfma_f32_16x16x32_bf16(af, wf[ks], accW, 0, 0, 0);
        accB = __builtin_amdgcn_mfma_f32_16x16x32_bf16(af, bf[ks], accB, 0, 0, 0);
    }

    // ---- epilogue: C layout col = m16 (u), row = q*4+rg
    #pragma unroll
    for (int rg = 0; rg < 4; ++rg) {
        const float nv2  = ((const float*)&nv4)[rg];
        const float dot1 = accW[rg];
        const float xy   = -accB[rg];
        const float dd   = 1.0f + 2.0f * xy + nb2 * nv2;
        const float inv_dd = __builtin_amdgcn_rcpf(dd);
        const float alpha  = (1.0f + 2.0f * xy + nv2) * inv_dd;
        const float beta   = one_m * inv_dd;
        const float num = 2.0f * one_m * (beta * dot1 - alpha * bw);
        const float mm  = alpha * alpha * nb2 + 2.0f * alpha * beta * xy
                        + beta * beta * nv2;
        const float den = (1.0f - mm) * a_norm;
        const float z   = num * __builtin_amdgcn_rcpf(den);
        const float s   = sqrtf(fmaf(z, z, 1.0f));
        logits[q * 4 + rg][u] = scale * copysignf(__logf(fabsf(z) + s), z);
    }
    __syncthreads();

    // ---- softmax: wave w handles row w, float4 I/O
    {
        const float4 v = *(const float4*)&logits[wave][lane * 4];
        float mx = fmaxf(fmaxf(v.x, v.y), fmaxf(v.z, v.w));
        #pragma unroll
        for (int off = 32; off; off >>= 1) mx = fmaxf(mx, __shfl_xor(mx, off));
        float4 e;
        e.x = __expf(v.x - mx);  e.y = __expf(v.y - mx);
        e.z = __expf(v.z - mx);  e.w = __expf(v.w - mx);
        float s = e.x + e.y + e.z + e.w;
        #pragma unroll
        for (int off = 32; off; off >>= 1) s += __shfl_xor(s, off);
        const float inv = __builtin_amdgcn_rcpf(s);
        e.x *= inv;  e.y *= inv;  e.z *= inv;  e.w *= inv;
        ((float4*)(out + (size_t)(b0 + wave) * UN))[lane] = e;
    }
}

extern "C" void kernel_launch(void* const* d_in, const int* in_sizes, int n_in,
                              void* d_out, int out_size, void* d_ws, size_t ws_size,
                              hipStream_t stream) {
    const float* x    = (const float*)d_in[0];
    const float* W    = (const float*)d_in[1];
    const float* bias = (const float*)d_in[2];
    float* out = (float*)d_out;
    (void)d_ws; (void)ws_size;

    hipLaunchKernelGGL(fused_kernel, dim3(BN / MROW), dim3(BLOCK), 0, stream,
                       x, W, bias, out);
}